// Round 6
// baseline (1461.284 us; speedup 1.0000x reference)
//
#include <hip/hip_runtime.h>
#include <hip/hip_bf16.h>

// Exact-match requirement for FPS/KNN index selection: no FMA contraction,
// replicate numpy fp32 expression order. Conv layers use explicit fmaf.
#pragma clang fp contract(off)

#define NPTS 8192
#define NS   1024
#define NB   2
#define NC   29
#define NK   16

// ---------------- workspace layout (bytes) ----------------
// nx      float[6144]    @ 8192
// knn     int[32768]     @ 32768
// w0t     float[73728]   @ 163840
// bias0   float[64]      @ 458752
// w1t     float[36864]   @ 459008
// w2t     float[73728]   @ 606464
// w3t     float[65536]   @ 901376

// ---------------- weight prep: transpose to [K][tap][O], fold ones-channels into bias0 ----------------
__global__ __launch_bounds__(256) void prep_kernel(
    const float* __restrict__ w0, const float* __restrict__ w1,
    const float* __restrict__ w2, const float* __restrict__ w3,
    float* __restrict__ w0t, float* __restrict__ w1t,
    float* __restrict__ w2t, float* __restrict__ w3t,
    float* __restrict__ bias0)
{
    int i = blockIdx.x * 256 + threadIdx.x;
    int n = gridDim.x * 256;
    for (int e = i; e < 73728; e += n) {
        int o = e & 63, r = e >> 6, tap = r % 9, ic2 = r / 9;
        int ic = ((ic2 >> 5) << 6) + (ic2 & 31);
        w0t[e] = w0[(o * 256 + ic) * 9 + tap];
    }
    for (int e = i; e < 36864; e += n) {
        int o = e & 63, r = e >> 6, tap = r % 9, ic = r / 9;
        w1t[e] = w1[(o * 64 + ic) * 9 + tap];
    }
    for (int e = i; e < 73728; e += n) {
        int o = e & 127, r = e >> 7, tap = r % 9, ic = r / 9;
        w2t[e] = w2[(o * 64 + ic) * 9 + tap];
    }
    for (int e = i; e < 65536; e += n) {
        int o = e & 127, r = e >> 7, tap = r & 3, ic = r >> 2;
        w3t[e] = w3[(o * 128 + ic) * 4 + tap];
    }
    if (i < 64) {
        float sum = 0.0f;
        for (int q = 0; q < 4; ++q)
            for (int c = 0; c < 32; ++c)
                for (int t = 0; t < 9; ++t)
                    sum += w0[(i * 256 + q * 64 + 32 + c) * 9 + t];
        bias0[i] = sum;
    }
}

// DPP wave64 max for non-negative floats (bound_ctrl zeros are identity for max).
__device__ __forceinline__ float wave_max_nonneg(float x) {
    int v = __float_as_int(x);
    int t;
    t = __builtin_amdgcn_update_dpp(0, v, 0x111, 0xf, 0xf, true);
    v = __float_as_int(fmaxf(__int_as_float(v), __int_as_float(t)));
    t = __builtin_amdgcn_update_dpp(0, v, 0x112, 0xf, 0xf, true);
    v = __float_as_int(fmaxf(__int_as_float(v), __int_as_float(t)));
    t = __builtin_amdgcn_update_dpp(0, v, 0x114, 0xf, 0xf, true);
    v = __float_as_int(fmaxf(__int_as_float(v), __int_as_float(t)));
    t = __builtin_amdgcn_update_dpp(0, v, 0x118, 0xf, 0xf, true);
    v = __float_as_int(fmaxf(__int_as_float(v), __int_as_float(t)));
    t = __builtin_amdgcn_update_dpp(0, v, 0x142, 0xa, 0xf, true);
    v = __float_as_int(fmaxf(__int_as_float(v), __int_as_float(t)));
    t = __builtin_amdgcn_update_dpp(0, v, 0x143, 0xc, 0xf, true);
    v = __float_as_int(fmaxf(__int_as_float(v), __int_as_float(t)));
    return __int_as_float(__builtin_amdgcn_readlane(v, 63));
}

// ---------------- FPS: one 512-thread block per batch, 16 pts/thread in regs ----------------
// FPS floor evidence (r0-r4): four structurally different variants all measure
// 1051-1058 us; wave count, barrier count, centroid-fetch tier are zero-delta.
// Per-iter time is pinned by the fixed reduce/sync round-trip chain at low
// effective clock (2-CU kernel). Do not re-tune.
__global__ __launch_bounds__(512, 2) void fps_kernel(
    const float* __restrict__ xyz,
    float* __restrict__ nx_ws, float* __restrict__ out)
{
    int b = blockIdx.x;
    int tid = threadIdx.x;              // 0..511
    const float* X = xyz + b * 3 * NPTS;

    __shared__ float s_xyz[3 * NPTS];              // 96 KB coord mirror
    __shared__ unsigned long long s_key[NS];       // 8 KB

    float px[16], py[16], pz[16], dist[16];
#pragma unroll
    for (int i = 0; i < 16; ++i) {
        int gi = i * 512 + tid;                    // point index
        float x = X[gi], y = X[NPTS + gi], z = X[2 * NPTS + gi];
        px[i] = x; py[i] = y; pz[i] = z;
        dist[i] = 1e10f;
        s_xyz[gi] = x; s_xyz[NPTS + gi] = y; s_xyz[2 * NPTS + gi] = z;
    }
    for (int i = tid; i < NS; i += 512) s_key[i] = 0ull;
    if (tid == 0) s_key[0] = 0xFFFFFFFFull;        // idx 0 forced (value unused)
    __syncthreads();

    float cx = s_xyz[0], cy = s_xyz[NPTS], cz = s_xyz[2 * NPTS];

    for (int it = 1; it < NS; ++it) {
        // pin coords in arch VGPRs each iteration (defeat AGPR/remat games)
#pragma unroll
        for (int i = 0; i < 16; ++i)
            asm volatile("" : "+v"(px[i]), "+v"(py[i]), "+v"(pz[i]));
        // ---- update dists (exact numpy order, no fma) ----
#pragma unroll
        for (int i = 0; i < 16; ++i) {
            float dx = px[i] - cx, dy = py[i] - cy, dz = pz[i] - cz;
            float d = (dx * dx + dy * dy) + dz * dz;
            dist[i] = fminf(dist[i], d);
        }
        // ---- local value max (tree, 15 ops) ----
        float t8[8];
#pragma unroll
        for (int i = 0; i < 8; ++i) t8[i] = fmaxf(dist[2 * i], dist[2 * i + 1]);
        float t4[4];
#pragma unroll
        for (int i = 0; i < 4; ++i) t4[i] = fmaxf(t8[2 * i], t8[2 * i + 1]);
        float bv = fmaxf(fmaxf(t4[0], t4[1]), fmaxf(t4[2], t4[3]));
        // ---- wave max via DPP; winner lanes resolve first-index + one atomic ----
        float wm = wave_max_nonneg(bv);
        if (bv == wm) {
            int gi = 0;
#pragma unroll
            for (int i = 15; i >= 0; --i)
                if (dist[i] == wm) gi = i * 512 + tid;   // ends at smallest i
            unsigned long long key =
                ((unsigned long long)__float_as_uint(wm) << 32) | (unsigned)(~gi);
            atomicMax(&s_key[it], key);
        }
        __syncthreads();
        int idx = (int)(~(unsigned)s_key[it]);
        // centroid re-fetch: broadcast ds_read x3 (uniform address)
        cx = s_xyz[idx]; cy = s_xyz[NPTS + idx]; cz = s_xyz[2 * NPTS + idx];
    }

    // ---- outputs: fps indices + gathered new_xyz (all slots final) ----
    float* out_fps = out + 268288 + b * NS;
    for (int i = tid; i < NS; i += 512) {
        int j = (int)(~(unsigned)s_key[i]);
        out_fps[i] = (float)j;
        float x = s_xyz[j], y = s_xyz[NPTS + j], z = s_xyz[2 * NPTS + j];
        nx_ws[(b * 3 + 0) * NS + i] = x; out[(b * 3 + 0) * NS + i] = x;
        nx_ws[(b * 3 + 1) * NS + i] = y; out[(b * 3 + 1) * NS + i] = y;
        nx_ws[(b * 3 + 2) * NS + i] = z; out[(b * 3 + 2) * NS + i] = z;
    }
}

// ---------------- KNN: one wave per query ----------------
__global__ __launch_bounds__(256) void knn_kernel(
    const float* __restrict__ nx_ws, int* __restrict__ knn_ws)
{
    int q = blockIdx.x * 4 + (threadIdx.x >> 6);
    int lane = threadIdx.x & 63;
    int b = q >> 10, s = q & 1023;
    const float* P = nx_ws + b * 3 * NS;
    float qx = P[s], qy = P[NS + s], qz = P[2 * NS + s];
    float sqq = (qx * qx + qy * qy) + qz * qz;
    int base_j = lane * 16;
    float d2[16];
    {
        const float4* x4 = (const float4*)(P + base_j);
        const float4* y4 = (const float4*)(P + NS + base_j);
        const float4* z4 = (const float4*)(P + 2 * NS + base_j);
#pragma unroll
        for (int t = 0; t < 4; ++t) {
            float4 xv = x4[t], yv = y4[t], zv = z4[t];
            float xs[4] = { xv.x, xv.y, xv.z, xv.w };
            float ys[4] = { yv.x, yv.y, yv.z, yv.w };
            float zs[4] = { zv.x, zv.y, zv.z, zv.w };
#pragma unroll
            for (int e = 0; e < 4; ++e) {
                float xj = xs[e], yj = ys[e], zj = zs[e];
                float sqj = (xj * xj + yj * yj) + zj * zj;
                float dot = (qx * xj + qy * yj) + qz * zj;
                d2[t * 4 + e] = (sqq + sqj) - 2.0f * dot;   // numpy order
            }
        }
    }
    for (int r = 0; r < NK; ++r) {
        float lv = 3.0e38f; int li = 0;
#pragma unroll
        for (int i = 0; i < 16; ++i) { if (d2[i] < lv) { lv = d2[i]; li = i; } } // strict < keeps earliest
        int gj = base_j + li;
#pragma unroll
        for (int off = 32; off > 0; off >>= 1) {
            float ov = __shfl_xor(lv, off, 64);
            int   oj = __shfl_xor(gj, off, 64);
            if (ov < lv || (ov == lv && oj < gj)) { lv = ov; gj = oj; }
        }
        if (lane == 0) knn_ws[q * NK + r] = gj;
        if ((gj >> 4) == lane) {
            int li2 = gj & 15;
#pragma unroll
            for (int i = 0; i < 16; ++i) if (i == li2) d2[i] = 3.0e38f;
        }
    }
}

// ---------------- conv0 with double-buffered LDS weight staging ----------------
// All 4 waves read the IDENTICAL w0t stream (g-independent) -> stage once per
// block. Chunk = 36 k-rows (4 ic2): reg-load chunk c+1 early, compute chunk c
// from LDS, ds_write late, barrier. Weight values and FMA order unchanged ->
// bit-identical output. G template keeps all array indices compile-time.
// Barrier counts are identical across all 4 instantiations (wave-uniform
// branch + equal-count s_barrier = safe wave specialization).
template<int G>
__device__ __forceinline__ void conv0_staged(
    const float* __restrict__ s_fg, float* __restrict__ s_w,
    const float* __restrict__ w0t, int o, float acc[9])
{
    constexpr int r0 = G + (G >> 1);         // {0,1,3,4}
    constexpr int GODD = G & 1;
    // prologue: stage chunk 0 into buffer 0
    {
        float st[9];
#pragma unroll
        for (int j = 0; j < 9; ++j) st[j] = w0t[(G * 9 + j) * 64 + o];
#pragma unroll
        for (int j = 0; j < 9; ++j) s_w[(G * 9 + j) * 64 + o] = st[j];
    }
    __syncthreads();
    int buf = 0;
#pragma unroll
    for (int q = 0; q < 4; ++q) {
        const int ro = q & 1, co = ((q + 1) >> 1) & 1;   // tl,br,tr,bl
        for (int cc = 0; cc < 8; ++cc) {
            int K = q * 8 + cc;
            float st[9];
            if (K < 31) {
                const float* gsrc = w0t + (K + 1) * 36 * 64;
#pragma unroll
                for (int j = 0; j < 9; ++j) st[j] = gsrc[(G * 9 + j) * 64 + o];
            }
            const float* wl = s_w + buf * 2304;
#pragma unroll
            for (int chl = 0; chl < 4; ++chl) {
                int ch = cc * 4 + chl;
                const float4* f4 = (const float4*)(s_fg + ch * 16);
                float4 v0 = f4[0], v1 = f4[1], v2 = f4[2], v3 = f4[3];
                float fg[16] = { v0.x, v0.y, v0.z, v0.w,  v1.x, v1.y, v1.z, v1.w,
                                 v2.x, v2.y, v2.z, v2.w,  v3.x, v3.y, v3.z, v3.w };
                float rr[32];
#pragma unroll
                for (int j = 0; j < 4; ++j) {
                    float aj = fg[2 * (r0 + j) + ro];
#pragma unroll
                    for (int v = 0; v < 8; ++v)
                        rr[j * 8 + v] = aj * fg[2 * v + co];
                }
                float w[9];
#pragma unroll
                for (int t = 0; t < 9; ++t) w[t] = wl[(chl * 9 + t) * 64 + o];
#pragma unroll
                for (int pp = 0; pp < 9; ++pp) {
                    const int ly = GODD ? (pp < 3 ? 0 : 1) : (pp < 6 ? 0 : 1);
                    const int xx = GODD ? (pp < 3 ? pp + 3 : pp - 3) : (pp < 6 ? pp : pp - 6);
#pragma unroll
                    for (int ky = 0; ky < 3; ++ky)
#pragma unroll
                        for (int kx = 0; kx < 3; ++kx)
                            acc[pp] = __builtin_fmaf(w[ky * 3 + kx], rr[(ly + ky) * 8 + xx + kx], acc[pp]);
                }
            }
            if (K < 31) {
                float* wn = s_w + (buf ^ 1) * 2304;
#pragma unroll
                for (int j = 0; j < 9; ++j) wn[(G * 9 + j) * 64 + o] = st[j];
            }
            __syncthreads();
            buf ^= 1;
        }
    }
}

// ---------------- per-sample conv chain ----------------
// conv0+conv1 weight streams staged through a shared 18KB LDS double-buffer:
// 4x less L2 weight traffic; LDS weight reads are stride-1 dwords (2
// lanes/bank = conflict-free). LDS ~35.9KB -> 4 blocks/CU at (256,4).
__global__ __launch_bounds__(256, 4) void conv_kernel(
    const float* __restrict__ feats, const float* __restrict__ nx_ws,
    const int* __restrict__ knn_ws,
    const float* __restrict__ w0t, const float* __restrict__ bias0,
    const float* __restrict__ w1t, const float* __restrict__ w2t,
    const float* __restrict__ w3t, float* __restrict__ out)
{
    __shared__ float s_fg[512];        // [d][k]
    __shared__ int   s_ni[16];
    __shared__ float s_w[2 * 36 * 64]; // 18KB weight staging dbuf
    __shared__ float s_a1[64 * 36];
    __shared__ float s_a2[64 * 16];
    __shared__ float s_a3[128 * 4];

    int bs = blockIdx.x, b = bs >> 10, s = bs & 1023;
    int tid = threadIdx.x;
    if (tid < 16) s_ni[tid] = knn_ws[bs * NK + tid];
    __syncthreads();
    const float* P = nx_ws + b * 3 * NS;
#pragma unroll
    for (int e = tid; e < 512; e += 256) {
        int d = e >> 4, k = e & 15; int j = s_ni[k];
        float v = (d < 3) ? (P[d * NS + j] - P[d * NS + s])
                          : feats[(b * NC + (d - 3)) * NPTS + j];
        s_fg[e] = v;
    }
    __syncthreads();

    int o = tid & 63, g = tid >> 6;
    { // conv0: 64 out-ch x 6x6, K = 128x9 (+ bias from ones-channels)
        float acc[9];
        float bz = bias0[o];
#pragma unroll
        for (int p = 0; p < 9; ++p) acc[p] = bz;
        if      (g == 0) conv0_staged<0>(s_fg, s_w, w0t, o, acc);
        else if (g == 1) conv0_staged<1>(s_fg, s_w, w0t, o, acc);
        else if (g == 2) conv0_staged<2>(s_fg, s_w, w0t, o, acc);
        else             conv0_staged<3>(s_fg, s_w, w0t, o, acc);
#pragma unroll
        for (int pp = 0; pp < 9; ++pp) s_a1[o * 36 + g * 9 + pp] = fmaxf(acc[pp], 0.0f);
    }
    // stage conv1 chunk 0 into buffer 0 (both buffers idle after conv0's final
    // barrier); merged with the s_a1 visibility barrier.
    {
        float st[9];
#pragma unroll
        for (int j = 0; j < 9; ++j) st[j] = w1t[(g * 9 + j) * 64 + o];
#pragma unroll
        for (int j = 0; j < 9; ++j) s_w[(g * 9 + j) * 64 + o] = st[j];
    }
    __syncthreads();
    { // conv1: 64 x 4x4, K = 64x9 ; y = g ; staged chunks of 4 ic
        float a[4] = {0, 0, 0, 0};
        int buf = 0;
        for (int c = 0; c < 16; ++c) {
            float st[9];
            if (c < 15) {
                const float* gsrc = w1t + (c + 1) * 36 * 64;
#pragma unroll
                for (int j = 0; j < 9; ++j) st[j] = gsrc[(g * 9 + j) * 64 + o];
            }
            const float* wl = s_w + buf * 2304;
#pragma unroll
            for (int icl = 0; icl < 4; ++icl) {
                int ic = c * 4 + icl;
                const float2* ar2 = (const float2*)(s_a1 + ic * 36 + g * 6);
                float r[18];
#pragma unroll
                for (int t = 0; t < 9; ++t) { float2 tv = ar2[t]; r[t*2] = tv.x; r[t*2+1] = tv.y; }
                float w[9];
#pragma unroll
                for (int t = 0; t < 9; ++t) w[t] = wl[(icl * 9 + t) * 64 + o];
#pragma unroll
                for (int x = 0; x < 4; ++x)
#pragma unroll
                    for (int ky = 0; ky < 3; ++ky)
#pragma unroll
                        for (int kx = 0; kx < 3; ++kx)
                            a[x] = __builtin_fmaf(w[ky * 3 + kx], r[ky * 6 + x + kx], a[x]);
            }
            if (c < 15) {
                float* wn = s_w + (buf ^ 1) * 2304;
#pragma unroll
                for (int j = 0; j < 9; ++j) wn[(g * 9 + j) * 64 + o] = st[j];
            }
            __syncthreads();
            buf ^= 1;
        }
#pragma unroll
        for (int x = 0; x < 4; ++x) s_a2[o * 16 + g * 4 + x] = fmaxf(a[x], 0.0f);
    }
    __syncthreads();
    { // conv2: 128 x 2x2, K = 64x9 ; y = g2
        int o2 = tid & 127, g2 = tid >> 7;
        float a[2] = {0, 0};
        const float* wb = w2t + o2;
        for (int ic = 0; ic < 64; ++ic) {
            const float4* ar4 = (const float4*)(s_a2 + ic * 16 + g2 * 4);
            float r[12];
#pragma unroll
            for (int t = 0; t < 3; ++t) { float4 tv = ar4[t]; r[t*4]=tv.x; r[t*4+1]=tv.y; r[t*4+2]=tv.z; r[t*4+3]=tv.w; }
            float w[9];
#pragma unroll
            for (int t = 0; t < 9; ++t) w[t] = wb[(ic * 9 + t) * 128];
#pragma unroll
            for (int x = 0; x < 2; ++x)
#pragma unroll
                for (int ky = 0; ky < 3; ++ky)
#pragma unroll
                    for (int kx = 0; kx < 3; ++kx)
                        a[x] = __builtin_fmaf(w[ky * 3 + kx], r[ky * 4 + x + kx], a[x]);
        }
#pragma unroll
        for (int x = 0; x < 2; ++x) s_a3[o2 * 4 + g2 * 2 + x] = fmaxf(a[x], 0.0f);
    }
    __syncthreads();
    // conv3: 128 out, K = 128x4 -> 1x1, relu, write new_points
    if (tid < 128) {
        float acc = 0.0f;
        const float* wb = w3t + tid;
        for (int ic = 0; ic < 128; ++ic) {
            float4 av = *(const float4*)(s_a3 + ic * 4);
            float wa = wb[(ic * 4 + 0) * 128];
            float wbv = wb[(ic * 4 + 1) * 128];
            float wc = wb[(ic * 4 + 2) * 128];
            float wd = wb[(ic * 4 + 3) * 128];
            acc = __builtin_fmaf(wa, av.x, acc);
            acc = __builtin_fmaf(wbv, av.y, acc);
            acc = __builtin_fmaf(wc, av.z, acc);
            acc = __builtin_fmaf(wd, av.w, acc);
        }
        out[6144 + (b * 128 + tid) * NS + s] = fmaxf(acc, 0.0f);
    }
}

extern "C" void kernel_launch(void* const* d_in, const int* in_sizes, int n_in,
                              void* d_out, int out_size, void* d_ws, size_t ws_size,
                              hipStream_t stream) {
    const float* xyz   = (const float*)d_in[0];
    const float* feats = (const float*)d_in[1];
    const float* w0    = (const float*)d_in[2];
    const float* w1    = (const float*)d_in[3];
    const float* w2    = (const float*)d_in[4];
    const float* w3    = (const float*)d_in[5];
    float* out = (float*)d_out;

    char* ws = (char*)d_ws;
    float* nx_ws  = (float*)(ws + 8192);
    int*   knn_ws = (int*)(ws + 32768);
    float* w0t    = (float*)(ws + 163840);
    float* bias0  = (float*)(ws + 458752);
    float* w1t    = (float*)(ws + 459008);
    float* w2t    = (float*)(ws + 606464);
    float* w3t    = (float*)(ws + 901376);

    prep_kernel<<<128, 256, 0, stream>>>(w0, w1, w2, w3, w0t, w1t, w2t, w3t, bias0);
    fps_kernel<<<NB, 512, 0, stream>>>(xyz, nx_ws, out);
    knn_kernel<<<(NB * NS) / 4, 256, 0, stream>>>(nx_ws, knn_ws);
    conv_kernel<<<NB * NS, 256, 0, stream>>>(feats, nx_ws, knn_ws, w0t, bias0, w1t, w2t, w3t, out);
}

// Round 7
// 1387.567 us; speedup vs baseline: 1.0531x; 1.0531x over previous
//
#include <hip/hip_runtime.h>
#include <hip/hip_bf16.h>

// Exact-match requirement for FPS/KNN index selection: no FMA contraction,
// replicate numpy fp32 expression order. Conv layers use explicit fmaf.
#pragma clang fp contract(off)

#define NPTS 8192
#define NS   1024
#define NB   2
#define NC   29
#define NK   16
#define FPS_GRID 256          // 2 real blocks + 254 clock-heater blocks

// ---------------- workspace layout (bytes) ----------------
// heat    uint[1]        @ 0       (clock-heater done-flag, zeroed by prep)
// nx      float[6144]    @ 8192
// knn     int[32768]     @ 32768
// w0t     float[73728]   @ 163840
// bias0   float[64]      @ 458752
// w1t     float[36864]   @ 459008
// w2t     float[73728]   @ 606464
// w3t     float[65536]   @ 901376

// ---------------- weight prep: transpose to [K][tap][O], fold ones-channels into bias0 ----------------
__global__ __launch_bounds__(256) void prep_kernel(
    const float* __restrict__ w0, const float* __restrict__ w1,
    const float* __restrict__ w2, const float* __restrict__ w3,
    float* __restrict__ w0t, float* __restrict__ w1t,
    float* __restrict__ w2t, float* __restrict__ w3t,
    float* __restrict__ bias0, unsigned* __restrict__ heat_flag)
{
    int i = blockIdx.x * 256 + threadIdx.x;
    int n = gridDim.x * 256;
    if (i == 0) *heat_flag = 0u;   // reset before fps dispatch (stream-ordered)
    for (int e = i; e < 73728; e += n) {
        int o = e & 63, r = e >> 6, tap = r % 9, ic2 = r / 9;
        int ic = ((ic2 >> 5) << 6) + (ic2 & 31);
        w0t[e] = w0[(o * 256 + ic) * 9 + tap];
    }
    for (int e = i; e < 36864; e += n) {
        int o = e & 63, r = e >> 6, tap = r % 9, ic = r / 9;
        w1t[e] = w1[(o * 64 + ic) * 9 + tap];
    }
    for (int e = i; e < 73728; e += n) {
        int o = e & 127, r = e >> 7, tap = r % 9, ic = r / 9;
        w2t[e] = w2[(o * 64 + ic) * 9 + tap];
    }
    for (int e = i; e < 65536; e += n) {
        int o = e & 127, r = e >> 7, tap = r & 3, ic = r >> 2;
        w3t[e] = w3[(o * 128 + ic) * 4 + tap];
    }
    if (i < 64) {
        float sum = 0.0f;
        for (int q = 0; q < 4; ++q)
            for (int c = 0; c < 32; ++c)
                for (int t = 0; t < 9; ++t)
                    sum += w0[(i * 256 + q * 64 + 32 + c) * 9 + t];
        bias0[i] = sum;
    }
}

// DPP wave64 max for non-negative floats (bound_ctrl zeros are identity for max).
__device__ __forceinline__ float wave_max_nonneg(float x) {
    int v = __float_as_int(x);
    int t;
    t = __builtin_amdgcn_update_dpp(0, v, 0x111, 0xf, 0xf, true);
    v = __float_as_int(fmaxf(__int_as_float(v), __int_as_float(t)));
    t = __builtin_amdgcn_update_dpp(0, v, 0x112, 0xf, 0xf, true);
    v = __float_as_int(fmaxf(__int_as_float(v), __int_as_float(t)));
    t = __builtin_amdgcn_update_dpp(0, v, 0x114, 0xf, 0xf, true);
    v = __float_as_int(fmaxf(__int_as_float(v), __int_as_float(t)));
    t = __builtin_amdgcn_update_dpp(0, v, 0x118, 0xf, 0xf, true);
    v = __float_as_int(fmaxf(__int_as_float(v), __int_as_float(t)));
    t = __builtin_amdgcn_update_dpp(0, v, 0x142, 0xa, 0xf, true);
    v = __float_as_int(fmaxf(__int_as_float(v), __int_as_float(t)));
    t = __builtin_amdgcn_update_dpp(0, v, 0x143, 0xc, 0xf, true);
    v = __float_as_int(fmaxf(__int_as_float(v), __int_as_float(t)));
    return __int_as_float(__builtin_amdgcn_readlane(v, 63));
}

// ---------------- FPS + clock heater ----------------
// FPS floor evidence (r0-r6): four structurally different variants all measure
// 1047-1058 us; wave/barrier/centroid-tier changes are zero-delta. Counter
// reconciliation (VALUBusy 0.53% chip = ~78% local on 2 CUs; hand-counted
// ~210 wave-instr/iter = ~840 issue-cyc/SIMD) matches an EFFECTIVE CLOCK of
// ~1 GHz, not 2.4 GHz: a 2-CU kernel leaves the chip 99.6% idle and the DPM
// governor down-clocks. THIS ROUND'S EXPERIMENT: blocks 2..255 are heaters
// that keep all CUs VALU-busy for the duration of FPS (exit via device-scope
// atomic flag; bounded loop as a hang guard). FPS math itself is untouched.
__global__ __launch_bounds__(512, 2) void fps_kernel(
    const float* __restrict__ xyz,
    float* __restrict__ nx_ws, float* __restrict__ out,
    unsigned* __restrict__ heat_flag)
{
    int b = blockIdx.x;
    int tid = threadIdx.x;              // 0..511

    __shared__ float s_xyz[3 * NPTS];              // 96 KB coord mirror
    __shared__ unsigned long long s_key[NS];       // 8 KB
    __shared__ int s_done;

    if (b >= NB) {
        // ---- clock heater: dependent-FMA spin until real blocks finish ----
        if (tid == 0) s_done = 0;
        __syncthreads();
        float a = 1.0f + (float)tid * 1e-7f;
        const float m = 1.0000001f;
        for (int outer = 0; outer < 4096; ++outer) {   // cap ~14ms: hang guard
#pragma unroll 64
            for (int k = 0; k < 2048; ++k)
                a = __builtin_fmaf(a, m, 1e-30f);
            asm volatile("" : "+v"(a));                 // keep chain live
            if (tid == 0) {
                if (atomicAdd(heat_flag, 0u) >= NB) s_done = 1;  // device-scope poll
            }
            if (*(volatile int*)&s_done) break;         // block-local fanout
        }
        return;
    }

    const float* X = xyz + b * 3 * NPTS;

    float px[16], py[16], pz[16], dist[16];
#pragma unroll
    for (int i = 0; i < 16; ++i) {
        int gi = i * 512 + tid;                    // point index
        float x = X[gi], y = X[NPTS + gi], z = X[2 * NPTS + gi];
        px[i] = x; py[i] = y; pz[i] = z;
        dist[i] = 1e10f;
        s_xyz[gi] = x; s_xyz[NPTS + gi] = y; s_xyz[2 * NPTS + gi] = z;
    }
    for (int i = tid; i < NS; i += 512) s_key[i] = 0ull;
    if (tid == 0) s_key[0] = 0xFFFFFFFFull;        // idx 0 forced (value unused)
    __syncthreads();

    float cx = s_xyz[0], cy = s_xyz[NPTS], cz = s_xyz[2 * NPTS];

    for (int it = 1; it < NS; ++it) {
        // pin coords in arch VGPRs each iteration (defeat AGPR/remat games)
#pragma unroll
        for (int i = 0; i < 16; ++i)
            asm volatile("" : "+v"(px[i]), "+v"(py[i]), "+v"(pz[i]));
        // ---- update dists (exact numpy order, no fma) ----
#pragma unroll
        for (int i = 0; i < 16; ++i) {
            float dx = px[i] - cx, dy = py[i] - cy, dz = pz[i] - cz;
            float d = (dx * dx + dy * dy) + dz * dz;
            dist[i] = fminf(dist[i], d);
        }
        // ---- local value max (tree, 15 ops) ----
        float t8[8];
#pragma unroll
        for (int i = 0; i < 8; ++i) t8[i] = fmaxf(dist[2 * i], dist[2 * i + 1]);
        float t4[4];
#pragma unroll
        for (int i = 0; i < 4; ++i) t4[i] = fmaxf(t8[2 * i], t8[2 * i + 1]);
        float bv = fmaxf(fmaxf(t4[0], t4[1]), fmaxf(t4[2], t4[3]));
        // ---- wave max via DPP; winner lanes resolve first-index + one atomic ----
        float wm = wave_max_nonneg(bv);
        if (bv == wm) {
            int gi = 0;
#pragma unroll
            for (int i = 15; i >= 0; --i)
                if (dist[i] == wm) gi = i * 512 + tid;   // ends at smallest i
            unsigned long long key =
                ((unsigned long long)__float_as_uint(wm) << 32) | (unsigned)(~gi);
            atomicMax(&s_key[it], key);
        }
        __syncthreads();
        int idx = (int)(~(unsigned)s_key[it]);
        // centroid re-fetch: broadcast ds_read x3 (uniform address)
        cx = s_xyz[idx]; cy = s_xyz[NPTS + idx]; cz = s_xyz[2 * NPTS + idx];
    }

    // ---- outputs: fps indices + gathered new_xyz (all slots final) ----
    float* out_fps = out + 268288 + b * NS;
    for (int i = tid; i < NS; i += 512) {
        int j = (int)(~(unsigned)s_key[i]);
        out_fps[i] = (float)j;
        float x = s_xyz[j], y = s_xyz[NPTS + j], z = s_xyz[2 * NPTS + j];
        nx_ws[(b * 3 + 0) * NS + i] = x; out[(b * 3 + 0) * NS + i] = x;
        nx_ws[(b * 3 + 1) * NS + i] = y; out[(b * 3 + 1) * NS + i] = y;
        nx_ws[(b * 3 + 2) * NS + i] = z; out[(b * 3 + 2) * NS + i] = z;
    }
    __syncthreads();
    if (tid == 0) atomicAdd(heat_flag, 1u);        // release the heaters
}

// ---------------- KNN: one wave per query ----------------
__global__ __launch_bounds__(256) void knn_kernel(
    const float* __restrict__ nx_ws, int* __restrict__ knn_ws)
{
    int q = blockIdx.x * 4 + (threadIdx.x >> 6);
    int lane = threadIdx.x & 63;
    int b = q >> 10, s = q & 1023;
    const float* P = nx_ws + b * 3 * NS;
    float qx = P[s], qy = P[NS + s], qz = P[2 * NS + s];
    float sqq = (qx * qx + qy * qy) + qz * qz;
    int base_j = lane * 16;
    float d2[16];
    {
        const float4* x4 = (const float4*)(P + base_j);
        const float4* y4 = (const float4*)(P + NS + base_j);
        const float4* z4 = (const float4*)(P + 2 * NS + base_j);
#pragma unroll
        for (int t = 0; t < 4; ++t) {
            float4 xv = x4[t], yv = y4[t], zv = z4[t];
            float xs[4] = { xv.x, xv.y, xv.z, xv.w };
            float ys[4] = { yv.x, yv.y, yv.z, yv.w };
            float zs[4] = { zv.x, zv.y, zv.z, zv.w };
#pragma unroll
            for (int e = 0; e < 4; ++e) {
                float xj = xs[e], yj = ys[e], zj = zs[e];
                float sqj = (xj * xj + yj * yj) + zj * zj;
                float dot = (qx * xj + qy * yj) + qz * zj;
                d2[t * 4 + e] = (sqq + sqj) - 2.0f * dot;   // numpy order
            }
        }
    }
    for (int r = 0; r < NK; ++r) {
        float lv = 3.0e38f; int li = 0;
#pragma unroll
        for (int i = 0; i < 16; ++i) { if (d2[i] < lv) { lv = d2[i]; li = i; } } // strict < keeps earliest
        int gj = base_j + li;
#pragma unroll
        for (int off = 32; off > 0; off >>= 1) {
            float ov = __shfl_xor(lv, off, 64);
            int   oj = __shfl_xor(gj, off, 64);
            if (ov < lv || (ov == lv && oj < gj)) { lv = ov; gj = oj; }
        }
        if (lane == 0) knn_ws[q * NK + r] = gj;
        if ((gj >> 4) == lane) {
            int li2 = gj & 15;
#pragma unroll
            for (int i = 0; i < 16; ++i) if (i == li2) d2[i] = 3.0e38f;
        }
    }
}

// ---------------- conv0 with double-buffered LDS weight staging ----------------
template<int G>
__device__ __forceinline__ void conv0_staged(
    const float* __restrict__ s_fg, float* __restrict__ s_w,
    const float* __restrict__ w0t, int o, float acc[9])
{
    constexpr int r0 = G + (G >> 1);         // {0,1,3,4}
    constexpr int GODD = G & 1;
    // prologue: stage chunk 0 into buffer 0
    {
        float st[9];
#pragma unroll
        for (int j = 0; j < 9; ++j) st[j] = w0t[(G * 9 + j) * 64 + o];
#pragma unroll
        for (int j = 0; j < 9; ++j) s_w[(G * 9 + j) * 64 + o] = st[j];
    }
    __syncthreads();
    int buf = 0;
#pragma unroll
    for (int q = 0; q < 4; ++q) {
        const int ro = q & 1, co = ((q + 1) >> 1) & 1;   // tl,br,tr,bl
        for (int cc = 0; cc < 8; ++cc) {
            int K = q * 8 + cc;
            float st[9];
            if (K < 31) {
                const float* gsrc = w0t + (K + 1) * 36 * 64;
#pragma unroll
                for (int j = 0; j < 9; ++j) st[j] = gsrc[(G * 9 + j) * 64 + o];
            }
            const float* wl = s_w + buf * 2304;
#pragma unroll
            for (int chl = 0; chl < 4; ++chl) {
                int ch = cc * 4 + chl;
                const float4* f4 = (const float4*)(s_fg + ch * 16);
                float4 v0 = f4[0], v1 = f4[1], v2 = f4[2], v3 = f4[3];
                float fg[16] = { v0.x, v0.y, v0.z, v0.w,  v1.x, v1.y, v1.z, v1.w,
                                 v2.x, v2.y, v2.z, v2.w,  v3.x, v3.y, v3.z, v3.w };
                float rr[32];
#pragma unroll
                for (int j = 0; j < 4; ++j) {
                    float aj = fg[2 * (r0 + j) + ro];
#pragma unroll
                    for (int v = 0; v < 8; ++v)
                        rr[j * 8 + v] = aj * fg[2 * v + co];
                }
                float w[9];
#pragma unroll
                for (int t = 0; t < 9; ++t) w[t] = wl[(chl * 9 + t) * 64 + o];
#pragma unroll
                for (int pp = 0; pp < 9; ++pp) {
                    const int ly = GODD ? (pp < 3 ? 0 : 1) : (pp < 6 ? 0 : 1);
                    const int xx = GODD ? (pp < 3 ? pp + 3 : pp - 3) : (pp < 6 ? pp : pp - 6);
#pragma unroll
                    for (int ky = 0; ky < 3; ++ky)
#pragma unroll
                        for (int kx = 0; kx < 3; ++kx)
                            acc[pp] = __builtin_fmaf(w[ky * 3 + kx], rr[(ly + ky) * 8 + xx + kx], acc[pp]);
                }
            }
            if (K < 31) {
                float* wn = s_w + (buf ^ 1) * 2304;
#pragma unroll
                for (int j = 0; j < 9; ++j) wn[(G * 9 + j) * 64 + o] = st[j];
            }
            __syncthreads();
            buf ^= 1;
        }
    }
}

// ---------------- per-sample conv chain ----------------
__global__ __launch_bounds__(256, 4) void conv_kernel(
    const float* __restrict__ feats, const float* __restrict__ nx_ws,
    const int* __restrict__ knn_ws,
    const float* __restrict__ w0t, const float* __restrict__ bias0,
    const float* __restrict__ w1t, const float* __restrict__ w2t,
    const float* __restrict__ w3t, float* __restrict__ out)
{
    __shared__ float s_fg[512];        // [d][k]
    __shared__ int   s_ni[16];
    __shared__ float s_w[2 * 36 * 64]; // 18KB weight staging dbuf
    __shared__ float s_a1[64 * 36];
    __shared__ float s_a2[64 * 16];
    __shared__ float s_a3[128 * 4];

    int bs = blockIdx.x, b = bs >> 10, s = bs & 1023;
    int tid = threadIdx.x;
    if (tid < 16) s_ni[tid] = knn_ws[bs * NK + tid];
    __syncthreads();
    const float* P = nx_ws + b * 3 * NS;
#pragma unroll
    for (int e = tid; e < 512; e += 256) {
        int d = e >> 4, k = e & 15; int j = s_ni[k];
        float v = (d < 3) ? (P[d * NS + j] - P[d * NS + s])
                          : feats[(b * NC + (d - 3)) * NPTS + j];
        s_fg[e] = v;
    }
    __syncthreads();

    int o = tid & 63, g = tid >> 6;
    { // conv0: 64 out-ch x 6x6, K = 128x9 (+ bias from ones-channels)
        float acc[9];
        float bz = bias0[o];
#pragma unroll
        for (int p = 0; p < 9; ++p) acc[p] = bz;
        if      (g == 0) conv0_staged<0>(s_fg, s_w, w0t, o, acc);
        else if (g == 1) conv0_staged<1>(s_fg, s_w, w0t, o, acc);
        else if (g == 2) conv0_staged<2>(s_fg, s_w, w0t, o, acc);
        else             conv0_staged<3>(s_fg, s_w, w0t, o, acc);
#pragma unroll
        for (int pp = 0; pp < 9; ++pp) s_a1[o * 36 + g * 9 + pp] = fmaxf(acc[pp], 0.0f);
    }
    // stage conv1 chunk 0 into buffer 0; merged with the s_a1 visibility barrier.
    {
        float st[9];
#pragma unroll
        for (int j = 0; j < 9; ++j) st[j] = w1t[(g * 9 + j) * 64 + o];
#pragma unroll
        for (int j = 0; j < 9; ++j) s_w[(g * 9 + j) * 64 + o] = st[j];
    }
    __syncthreads();
    { // conv1: 64 x 4x4, K = 64x9 ; y = g ; staged chunks of 4 ic
        float a[4] = {0, 0, 0, 0};
        int buf = 0;
        for (int c = 0; c < 16; ++c) {
            float st[9];
            if (c < 15) {
                const float* gsrc = w1t + (c + 1) * 36 * 64;
#pragma unroll
                for (int j = 0; j < 9; ++j) st[j] = gsrc[(g * 9 + j) * 64 + o];
            }
            const float* wl = s_w + buf * 2304;
#pragma unroll
            for (int icl = 0; icl < 4; ++icl) {
                int ic = c * 4 + icl;
                const float2* ar2 = (const float2*)(s_a1 + ic * 36 + g * 6);
                float r[18];
#pragma unroll
                for (int t = 0; t < 9; ++t) { float2 tv = ar2[t]; r[t*2] = tv.x; r[t*2+1] = tv.y; }
                float w[9];
#pragma unroll
                for (int t = 0; t < 9; ++t) w[t] = wl[(icl * 9 + t) * 64 + o];
#pragma unroll
                for (int x = 0; x < 4; ++x)
#pragma unroll
                    for (int ky = 0; ky < 3; ++ky)
#pragma unroll
                        for (int kx = 0; kx < 3; ++kx)
                            a[x] = __builtin_fmaf(w[ky * 3 + kx], r[ky * 6 + x + kx], a[x]);
            }
            if (c < 15) {
                float* wn = s_w + (buf ^ 1) * 2304;
#pragma unroll
                for (int j = 0; j < 9; ++j) wn[(g * 9 + j) * 64 + o] = st[j];
            }
            __syncthreads();
            buf ^= 1;
        }
#pragma unroll
        for (int x = 0; x < 4; ++x) s_a2[o * 16 + g * 4 + x] = fmaxf(a[x], 0.0f);
    }
    __syncthreads();
    { // conv2: 128 x 2x2, K = 64x9 ; y = g2
        int o2 = tid & 127, g2 = tid >> 7;
        float a[2] = {0, 0};
        const float* wb = w2t + o2;
        for (int ic = 0; ic < 64; ++ic) {
            const float4* ar4 = (const float4*)(s_a2 + ic * 16 + g2 * 4);
            float r[12];
#pragma unroll
            for (int t = 0; t < 3; ++t) { float4 tv = ar4[t]; r[t*4]=tv.x; r[t*4+1]=tv.y; r[t*4+2]=tv.z; r[t*4+3]=tv.w; }
            float w[9];
#pragma unroll
            for (int t = 0; t < 9; ++t) w[t] = wb[(ic * 9 + t) * 128];
#pragma unroll
            for (int x = 0; x < 2; ++x)
#pragma unroll
                for (int ky = 0; ky < 3; ++ky)
#pragma unroll
                    for (int kx = 0; kx < 3; ++kx)
                        a[x] = __builtin_fmaf(w[ky * 3 + kx], r[ky * 4 + x + kx], a[x]);
        }
#pragma unroll
        for (int x = 0; x < 2; ++x) s_a3[o2 * 4 + g2 * 2 + x] = fmaxf(a[x], 0.0f);
    }
    __syncthreads();
    // conv3: 128 out, K = 128x4 -> 1x1, relu, write new_points
    if (tid < 128) {
        float acc = 0.0f;
        const float* wb = w3t + tid;
        for (int ic = 0; ic < 128; ++ic) {
            float4 av = *(const float4*)(s_a3 + ic * 4);
            float wa = wb[(ic * 4 + 0) * 128];
            float wbv = wb[(ic * 4 + 1) * 128];
            float wc = wb[(ic * 4 + 2) * 128];
            float wd = wb[(ic * 4 + 3) * 128];
            acc = __builtin_fmaf(wa, av.x, acc);
            acc = __builtin_fmaf(wbv, av.y, acc);
            acc = __builtin_fmaf(wc, av.z, acc);
            acc = __builtin_fmaf(wd, av.w, acc);
        }
        out[6144 + (b * 128 + tid) * NS + s] = fmaxf(acc, 0.0f);
    }
}

extern "C" void kernel_launch(void* const* d_in, const int* in_sizes, int n_in,
                              void* d_out, int out_size, void* d_ws, size_t ws_size,
                              hipStream_t stream) {
    const float* xyz   = (const float*)d_in[0];
    const float* feats = (const float*)d_in[1];
    const float* w0    = (const float*)d_in[2];
    const float* w1    = (const float*)d_in[3];
    const float* w2    = (const float*)d_in[4];
    const float* w3    = (const float*)d_in[5];
    float* out = (float*)d_out;

    char* ws = (char*)d_ws;
    unsigned* heat = (unsigned*)ws;                 // @0
    float* nx_ws  = (float*)(ws + 8192);
    int*   knn_ws = (int*)(ws + 32768);
    float* w0t    = (float*)(ws + 163840);
    float* bias0  = (float*)(ws + 458752);
    float* w1t    = (float*)(ws + 459008);
    float* w2t    = (float*)(ws + 606464);
    float* w3t    = (float*)(ws + 901376);

    prep_kernel<<<128, 256, 0, stream>>>(w0, w1, w2, w3, w0t, w1t, w2t, w3t, bias0, heat);
    fps_kernel<<<FPS_GRID, 512, 0, stream>>>(xyz, nx_ws, out, heat);
    knn_kernel<<<(NB * NS) / 4, 256, 0, stream>>>(nx_ws, knn_ws);
    conv_kernel<<<NB * NS, 256, 0, stream>>>(feats, nx_ws, knn_ws, w0t, bias0, w1t, w2t, w3t, out);
}